// Round 6
// baseline (263.598 us; speedup 1.0000x reference)
//
#include <hip/hip_runtime.h>
#include <math.h>

#define B 4
#define P 32768
#define C 8
#define F 32
#define D 64
#define H 64
#define RS 72   // LDS row stride in shorts

typedef __attribute__((ext_vector_type(8))) short bf16x8;
typedef __attribute__((ext_vector_type(4))) float f32x4;

__device__ __forceinline__ short f2bf(float f) {
    union { float f; unsigned u; } v; v.f = f;
    unsigned r = (v.u + 0x7FFFu + ((v.u >> 16) & 1u)) >> 16;   // RNE
    return (short)r;
}

// pack two fp32 -> one dword of two RNE bf16 (low = a, high = b)
__device__ __forceinline__ unsigned pk2bf(float a, float b) {
    unsigned ua = __float_as_uint(a);
    unsigned ub = __float_as_uint(b);
    ua += 0x7FFFu + ((ua >> 16) & 1u);
    ub += 0x7FFFu + ((ub >> 16) & 1u);
    return __builtin_amdgcn_perm(ub, ua, 0x07060302u);
}

// ---------------------------------------------------------------------------
// Merged setup kernel (unchanged from R5 — correct & fast enough).
// blocks [0,32):  per-(b,c) Bxt build; blocks [32,112): Wa/Wb transpose.
// n-major storage uses COLUMN PERMUTATION s=(a%4)*16+a/4 so the MFMA
// C-layout's 4 per-lane values are memory-adjacent on the LDS write side.
// ---------------------------------------------------------------------------
__global__ __launch_bounds__(256)
void setup_kernel(const float* __restrict__ z,
                  const float* __restrict__ W_dir,
                  const float* __restrict__ W0,
                  const float* __restrict__ b0,
                  const float* __restrict__ Wa,
                  const float* __restrict__ Wb,
                  short* __restrict__ Bxt,
                  short* __restrict__ Wat,
                  short* __restrict__ Wbt)
{
    if (blockIdx.x >= 32) {
        int idx = (blockIdx.x - 32) * 256 + threadIdx.x;  // < 5*64*64
        int i = idx >> 12, r = idx & 4095, k = r >> 6, n = r & 63;
        int s = (n & 3) * 16 + (n >> 2);                  // permuted storage row
        int o = (i << 12) + (s << 6) + k;
        Wat[o] = f2bf(Wa[idx]);
        Wbt[o] = f2bf(Wb[idx]);
        return;
    }
    const int bc = blockIdx.x;
    const int t  = threadIdx.x & 63;     // actual output column
    const int g  = threadIdx.x >> 6;     // group 0..3
    const float* zb = z + (size_t)bc * F * D;

    __shared__ float zl[F][D];
    __shared__ float zp[4][D];
    __shared__ float zq[4][D];

    for (int i = threadIdx.x; i < F * D; i += 256) zl[i >> 6][i & 63] = zb[i];
    __syncthreads();

    const int srow = (t & 3) * 16 + (t >> 2);
    short* brow = Bxt + ((size_t)bc * 64 + srow) * 64;

    float zi = 0.f;
    for (int f = g * 8; f < g * 8 + 8; ++f) {
        float z0 = 0, z1 = 0, z2 = 0, z3 = 0;
        float a0 = 0, a1 = 0, a2 = 0, a3 = 0;
        for (int d = 0; d < D; d += 4) {
            z0 += zl[f][d + 0] * W_dir[(d + 0) * D + t];
            z1 += zl[f][d + 1] * W_dir[(d + 1) * D + t];
            z2 += zl[f][d + 2] * W_dir[(d + 2) * D + t];
            z3 += zl[f][d + 3] * W_dir[(d + 3) * D + t];
            a0 += zl[f][d + 0] * W0[(1 + d + 0) * H + t];
            a1 += zl[f][d + 1] * W0[(1 + d + 1) * H + t];
            a2 += zl[f][d + 2] * W0[(1 + d + 2) * H + t];
            a3 += zl[f][d + 3] * W0[(1 + d + 3) * H + t];
        }
        zi += zl[f][t] * ((z0 + z1) + (z2 + z3));
        brow[f] = f2bf((a0 + a1) + (a2 + a3));
    }
    zp[g][t] = zi;
    __syncthreads();
    if (g == 0) zp[0][t] = zp[0][t] + zp[1][t] + zp[2][t] + zp[3][t];  // z_inv
    __syncthreads();
    {
        float acc = 0.f;
        for (int e = g * 16; e < g * 16 + 16; ++e)
            acc += zp[0][e] * W0[(65 + e) * H + t];
        zq[g][t] = acc;
    }
    __syncthreads();
    if (g == 0) {
        brow[32] = f2bf(W0[t]);
        brow[33] = f2bf(b0[t] + zq[0][t] + zq[1][t] + zq[2][t] + zq[3][t]);
    } else if (g == 1) {
        for (int k = 34; k < 64; ++k) brow[k] = 0;
    }
}

// ---------------------------------------------------------------------------
// Main: 4 waves/block; wave = 16 points, ONE channel per c-iter.
// Register-lean by design: persistent = a-frags(8) + pooled(16) + biases(8);
// all 8 weight-fragment loads of a stage are BATCHED into arrays so they
// pipeline as independent global_load_dwordx4 (R4/R5 showed serialized
// frag-load stalls ~200cyc each were the real bottleneck, not LDS).
// launch_bounds(256,4): cap 128 VGPR -> 4 waves/SIMD. c-loop and layer
// loop kept rolled (#pragma unroll 1) to keep the body I$-small.
// ---------------------------------------------------------------------------
__global__ __launch_bounds__(256, 4)
void main_kernel(const float* __restrict__ p,      // (B,P,3)
                 const float* __restrict__ pos,    // (B,3)
                 const float* __restrict__ W_feat, // (3,F)
                 const short* __restrict__ Bxt,    // (B,C,64s,64k) bf16 (perm cols)
                 const short* __restrict__ Wat,    // (5,64s,64k)
                 const short* __restrict__ Wbt,    // (5,64s,64k)
                 const float* __restrict__ ba,     // (5,H)
                 const float* __restrict__ bb,     // (5,H)
                 const float* __restrict__ Wout,   // (H,1)
                 const float* __restrict__ bout,   // (1,)
                 float* __restrict__ out)          // (B,P)
{
    const int wave = threadIdx.x >> 6;
    const int lane = threadIdx.x & 63;
    const int quad = lane >> 4;
    const int l16  = lane & 15;
    const int b    = blockIdx.y;
    const int base = blockIdx.x * 64 + wave * 16;

    __shared__ short lds[4][16 * RS];             // 18.4 KB
    short* buf = &lds[wave][0];

    // ---- point features -> A-frags
    bf16x8 a0, a1;
    {
        const float* pp = p + ((size_t)b * P + base + l16) * 3;
        float px = pp[0] - pos[b * 3 + 0];
        float py = pp[1] - pos[b * 3 + 1];
        float pz = pp[2] - pos[b * 3 + 2];
        float nrm = sqrtf(px * px + py * py + pz * pz);
        if (nrm > 0.5f) { float s = 0.5f / nrm; px *= s; py *= s; pz *= s; }
        float s2 = 0.f;
#pragma unroll
        for (int j = 0; j < 8; ++j) {
            int k = quad * 8 + j;
            float a = px * W_feat[k] + py * W_feat[F + k] + pz * W_feat[2 * F + k];
            a0[j] = f2bf(a);
            s2 += a * a;
        }
        s2 += __shfl_xor(s2, 16);
        s2 += __shfl_xor(s2, 32);
#pragma unroll
        for (int j = 0; j < 8; ++j) a1[j] = 0;
        if (quad == 0) { a1[0] = f2bf(s2); a1[1] = f2bf(1.0f); }
    }

    f32x4 pooled[4];
#pragma unroll
    for (int nt = 0; nt < 4; ++nt)
        pooled[nt] = (f32x4){-1e30f, -1e30f, -1e30f, -1e30f};

    const float4 ba0v = *(const float4*)(ba + 4 * l16);
    const float4 bb0v = *(const float4*)(bb + 4 * l16);

    const int fragOff = l16 * 64 + quad * 8;      // row l16 (+nt*16 below), cols quad*8..+7

    // =============== c-loop: one channel per iter ===========================
#pragma unroll 1
    for (int c = 0; c < C; ++c) {
        const short* bx = Bxt + ((size_t)(b * C + c)) * 4096;

        // ---- stage 1: x = A' @ Bx   (batch all 8 frag loads)
        bf16x8 bw0[4], bw1[4];
#pragma unroll
        for (int nt = 0; nt < 4; ++nt) {
            bw0[nt] = *(const bf16x8*)(bx + nt * 1024 + fragOff);
            bw1[nt] = *(const bf16x8*)(bx + nt * 1024 + fragOff + 32);
        }
        f32x4 x[4];
#pragma unroll
        for (int nt = 0; nt < 4; ++nt) {
            f32x4 acc = (f32x4){0.f, 0.f, 0.f, 0.f};
            acc = __builtin_amdgcn_mfma_f32_16x16x32_bf16(a0, bw0[nt], acc, 0, 0, 0);
            acc = __builtin_amdgcn_mfma_f32_16x16x32_bf16(a1, bw1[nt], acc, 0, 0, 0);
            x[nt] = acc;
        }

        // ---- relu(x) -> LDS -> A-frags
#pragma unroll
        for (int r = 0; r < 4; ++r) {
            uint2 w;
            w.x = pk2bf(fmaxf(x[0][r], 0.f), fmaxf(x[1][r], 0.f));
            w.y = pk2bf(fmaxf(x[2][r], 0.f), fmaxf(x[3][r], 0.f));
            *(uint2*)(buf + (quad * 4 + r) * RS + 4 * l16) = w;
        }
        bf16x8 xa0 = *(const bf16x8*)(buf + l16 * RS + quad * 8);
        bf16x8 xa1 = *(const bf16x8*)(buf + l16 * RS + 32 + quad * 8);

        // ---- stage 2: h = relu(x) @ Wa0 + ba0   (batched frags; L1-hot)
        bf16x8 w0f[4], w1f[4];
#pragma unroll
        for (int nt = 0; nt < 4; ++nt) {
            w0f[nt] = *(const bf16x8*)(Wat + nt * 1024 + fragOff);
            w1f[nt] = *(const bf16x8*)(Wat + nt * 1024 + fragOff + 32);
        }
        f32x4 h[4];
#pragma unroll
        for (int nt = 0; nt < 4; ++nt) {
            float bv = nt == 0 ? ba0v.x : nt == 1 ? ba0v.y : nt == 2 ? ba0v.z : ba0v.w;
            f32x4 acc = (f32x4){bv, bv, bv, bv};
            acc = __builtin_amdgcn_mfma_f32_16x16x32_bf16(xa0, w0f[nt], acc, 0, 0, 0);
            acc = __builtin_amdgcn_mfma_f32_16x16x32_bf16(xa1, w1f[nt], acc, 0, 0, 0);
            h[nt] = acc;
        }

        // ---- relu(h) -> LDS -> A-frags
#pragma unroll
        for (int r = 0; r < 4; ++r) {
            uint2 w;
            w.x = pk2bf(fmaxf(h[0][r], 0.f), fmaxf(h[1][r], 0.f));
            w.y = pk2bf(fmaxf(h[2][r], 0.f), fmaxf(h[3][r], 0.f));
            *(uint2*)(buf + (quad * 4 + r) * RS + 4 * l16) = w;
        }
        bf16x8 ha0 = *(const bf16x8*)(buf + l16 * RS + quad * 8);
        bf16x8 ha1 = *(const bf16x8*)(buf + l16 * RS + 32 + quad * 8);

        // ---- stage 3: pool( x + relu(h) @ Wb0 )   [bb0 deferred]
#pragma unroll
        for (int nt = 0; nt < 4; ++nt) {
            w0f[nt] = *(const bf16x8*)(Wbt + nt * 1024 + fragOff);
            w1f[nt] = *(const bf16x8*)(Wbt + nt * 1024 + fragOff + 32);
        }
#pragma unroll
        for (int nt = 0; nt < 4; ++nt) {
            f32x4 acc = x[nt];
            acc = __builtin_amdgcn_mfma_f32_16x16x32_bf16(ha0, w0f[nt], acc, 0, 0, 0);
            acc = __builtin_amdgcn_mfma_f32_16x16x32_bf16(ha1, w1f[nt], acc, 0, 0, 0);
#pragma unroll
            for (int r = 0; r < 4; ++r)
                pooled[nt][r] = fmaxf(pooled[nt][r], acc[r]);
        }
    }

    // deferred bb0
#pragma unroll
    for (int nt = 0; nt < 4; ++nt) {
        float bv = nt == 0 ? bb0v.x : nt == 1 ? bb0v.y : nt == 2 ? bb0v.z : bb0v.w;
#pragma unroll
        for (int r = 0; r < 4; ++r) pooled[nt][r] += bv;
    }

    // =============== residual blocks 1..4 (rolled) ==========================
#pragma unroll 1
    for (int i = 1; i < 5; ++i) {
        const short* wa = Wat + i * 4096;
        const short* wb = Wbt + i * 4096;
        const float4 bai = *(const float4*)(ba + i * H + 4 * l16);
        const float4 bbi = *(const float4*)(bb + i * H + 4 * l16);

#pragma unroll
        for (int r = 0; r < 4; ++r) {
            uint2 w;
            w.x = pk2bf(fmaxf(pooled[0][r], 0.f), fmaxf(pooled[1][r], 0.f));
            w.y = pk2bf(fmaxf(pooled[2][r], 0.f), fmaxf(pooled[3][r], 0.f));
            *(uint2*)(buf + (quad * 4 + r) * RS + 4 * l16) = w;
        }
        bf16x8 xa0 = *(const bf16x8*)(buf + l16 * RS + quad * 8);
        bf16x8 xa1 = *(const bf16x8*)(buf + l16 * RS + 32 + quad * 8);

        bf16x8 w0f[4], w1f[4];
#pragma unroll
        for (int nt = 0; nt < 4; ++nt) {
            w0f[nt] = *(const bf16x8*)(wa + nt * 1024 + fragOff);
            w1f[nt] = *(const bf16x8*)(wa + nt * 1024 + fragOff + 32);
        }
        f32x4 h[4];
#pragma unroll
        for (int nt = 0; nt < 4; ++nt) {
            float bv = nt == 0 ? bai.x : nt == 1 ? bai.y : nt == 2 ? bai.z : bai.w;
            f32x4 acc = (f32x4){bv, bv, bv, bv};
            acc = __builtin_amdgcn_mfma_f32_16x16x32_bf16(xa0, w0f[nt], acc, 0, 0, 0);
            acc = __builtin_amdgcn_mfma_f32_16x16x32_bf16(xa1, w1f[nt], acc, 0, 0, 0);
            h[nt] = acc;
        }

#pragma unroll
        for (int r = 0; r < 4; ++r) {
            uint2 w;
            w.x = pk2bf(fmaxf(h[0][r], 0.f), fmaxf(h[1][r], 0.f));
            w.y = pk2bf(fmaxf(h[2][r], 0.f), fmaxf(h[3][r], 0.f));
            *(uint2*)(buf + (quad * 4 + r) * RS + 4 * l16) = w;
        }
        bf16x8 ha0 = *(const bf16x8*)(buf + l16 * RS + quad * 8);
        bf16x8 ha1 = *(const bf16x8*)(buf + l16 * RS + 32 + quad * 8);

#pragma unroll
        for (int nt = 0; nt < 4; ++nt) {
            w0f[nt] = *(const bf16x8*)(wb + nt * 1024 + fragOff);
            w1f[nt] = *(const bf16x8*)(wb + nt * 1024 + fragOff + 32);
        }
#pragma unroll
        for (int nt = 0; nt < 4; ++nt) {
            float bv = nt == 0 ? bbi.x : nt == 1 ? bbi.y : nt == 2 ? bbi.z : bbi.w;
            f32x4 acc = pooled[nt];
#pragma unroll
            for (int r = 0; r < 4; ++r) acc[r] += bv;
            acc = __builtin_amdgcn_mfma_f32_16x16x32_bf16(ha0, w0f[nt], acc, 0, 0, 0);
            acc = __builtin_amdgcn_mfma_f32_16x16x32_bf16(ha1, w1f[nt], acc, 0, 0, 0);
            pooled[nt] = acc;
        }
    }

    // =============== head ===================================================
    const float4 wo4 = *(const float4*)(Wout + 4 * l16);
    const float bo = bout[0];
    float o[4];
#pragma unroll
    for (int r = 0; r < 4; ++r) {
        float v = fmaxf(pooled[0][r], 0.f) * wo4.x
                + fmaxf(pooled[1][r], 0.f) * wo4.y
                + fmaxf(pooled[2][r], 0.f) * wo4.z
                + fmaxf(pooled[3][r], 0.f) * wo4.w;
        v += __shfl_xor(v, 1);
        v += __shfl_xor(v, 2);
        v += __shfl_xor(v, 4);
        v += __shfl_xor(v, 8);
        o[r] = v + bo;
    }
    if (l16 == 0) {
        *(float4*)(out + (size_t)b * P + base + quad * 4) =
            make_float4(o[0], o[1], o[2], o[3]);
    }
}

extern "C" void kernel_launch(void* const* d_in, const int* in_sizes, int n_in,
                              void* d_out, int out_size, void* d_ws, size_t ws_size,
                              hipStream_t stream) {
    const float* z      = (const float*)d_in[0];
    const float* pos    = (const float*)d_in[1];
    const float* p      = (const float*)d_in[2];
    const float* W_feat = (const float*)d_in[3];
    const float* W_dir  = (const float*)d_in[4];
    const float* W0     = (const float*)d_in[5];
    const float* b0     = (const float*)d_in[6];
    const float* Wa     = (const float*)d_in[7];
    const float* ba     = (const float*)d_in[8];
    const float* Wb     = (const float*)d_in[9];
    const float* bb     = (const float*)d_in[10];
    const float* Wout   = (const float*)d_in[11];
    const float* bout   = (const float*)d_in[12];
    float* out = (float*)d_out;

    short* wsS = (short*)d_ws;
    short* Bxt = wsS;                    // B*C*64*64 shorts
    short* Wat = wsS + 32 * 4096;        // 5*4096
    short* Wbt = Wat + 5 * 4096;         // 5*4096

    setup_kernel<<<112, 256, 0, stream>>>(z, W_dir, W0, b0, Wa, Wb, Bxt, Wat, Wbt);

    dim3 grid(P / 64, B);
    main_kernel<<<grid, 256, 0, stream>>>(p, pos, W_feat, Bxt, Wat, Wbt,
                                          ba, bb, Wout, bout, out);
}

// Round 8
// 215.017 us; speedup vs baseline: 1.2259x; 1.2259x over previous
//
#include <hip/hip_runtime.h>
#include <math.h>

#define B 4
#define P 32768
#define C 8
#define F 32
#define D 64
#define H 64
#define RS 72   // LDS row stride in shorts

typedef __attribute__((ext_vector_type(8))) short bf16x8;
typedef __attribute__((ext_vector_type(4))) float f32x4;

__device__ __forceinline__ short f2bf(float f) {
    union { float f; unsigned u; } v; v.f = f;
    unsigned r = (v.u + 0x7FFFu + ((v.u >> 16) & 1u)) >> 16;   // RNE
    return (short)r;
}

// packed cvt: two fp32 -> dword of two RNE bf16 (a low, b high)
#if defined(__has_builtin) && __has_builtin(__builtin_amdgcn_cvt_pk_bf16_f32)
typedef __attribute__((ext_vector_type(2))) __bf16 bf16x2;
__device__ __forceinline__ unsigned cvtpk(float a, float b) {
    bf16x2 t = __builtin_amdgcn_cvt_pk_bf16_f32(a, b);   // v_cvt_pk_bf16_f32: lo=a, hi=b
    union { bf16x2 h; unsigned u; } v; v.h = t;
    return v.u;
}
#else
__device__ __forceinline__ unsigned cvtpk(float a, float b) {
    unsigned ua = __float_as_uint(a);
    unsigned ub = __float_as_uint(b);
    ua += 0x7FFFu + ((ua >> 16) & 1u);
    ub += 0x7FFFu + ((ub >> 16) & 1u);
    return __builtin_amdgcn_perm(ub, ua, 0x07060302u);
}
#endif

// ---------------------------------------------------------------------------
// Merged setup kernel (unchanged — correct & fast enough).
// blocks [0,32):  per-(b,c) Bxt build; blocks [32,112): Wa/Wb transpose.
// n-major storage uses COLUMN PERMUTATION s=(a%4)*16+a/4 so the MFMA
// C-layout's 4 per-lane values are memory-adjacent on the LDS write side.
// ---------------------------------------------------------------------------
__global__ __launch_bounds__(256)
void setup_kernel(const float* __restrict__ z,
                  const float* __restrict__ W_dir,
                  const float* __restrict__ W0,
                  const float* __restrict__ b0,
                  const float* __restrict__ Wa,
                  const float* __restrict__ Wb,
                  short* __restrict__ Bxt,
                  short* __restrict__ Wat,
                  short* __restrict__ Wbt)
{
    if (blockIdx.x >= 32) {
        int idx = (blockIdx.x - 32) * 256 + threadIdx.x;  // < 5*64*64
        int i = idx >> 12, r = idx & 4095, k = r >> 6, n = r & 63;
        int s = (n & 3) * 16 + (n >> 2);                  // permuted storage row
        int o = (i << 12) + (s << 6) + k;
        Wat[o] = f2bf(Wa[idx]);
        Wbt[o] = f2bf(Wb[idx]);
        return;
    }
    const int bc = blockIdx.x;
    const int t  = threadIdx.x & 63;     // actual output column
    const int g  = threadIdx.x >> 6;     // group 0..3
    const float* zb = z + (size_t)bc * F * D;

    __shared__ float zl[F][D];
    __shared__ float zp[4][D];
    __shared__ float zq[4][D];

    for (int i = threadIdx.x; i < F * D; i += 256) zl[i >> 6][i & 63] = zb[i];
    __syncthreads();

    const int srow = (t & 3) * 16 + (t >> 2);
    short* brow = Bxt + ((size_t)bc * 64 + srow) * 64;

    float zi = 0.f;
    for (int f = g * 8; f < g * 8 + 8; ++f) {
        float z0 = 0, z1 = 0, z2 = 0, z3 = 0;
        float a0 = 0, a1 = 0, a2 = 0, a3 = 0;
        for (int d = 0; d < D; d += 4) {
            z0 += zl[f][d + 0] * W_dir[(d + 0) * D + t];
            z1 += zl[f][d + 1] * W_dir[(d + 1) * D + t];
            z2 += zl[f][d + 2] * W_dir[(d + 2) * D + t];
            z3 += zl[f][d + 3] * W_dir[(d + 3) * D + t];
            a0 += zl[f][d + 0] * W0[(1 + d + 0) * H + t];
            a1 += zl[f][d + 1] * W0[(1 + d + 1) * H + t];
            a2 += zl[f][d + 2] * W0[(1 + d + 2) * H + t];
            a3 += zl[f][d + 3] * W0[(1 + d + 3) * H + t];
        }
        zi += zl[f][t] * ((z0 + z1) + (z2 + z3));
        brow[f] = f2bf((a0 + a1) + (a2 + a3));
    }
    zp[g][t] = zi;
    __syncthreads();
    if (g == 0) zp[0][t] = zp[0][t] + zp[1][t] + zp[2][t] + zp[3][t];  // z_inv
    __syncthreads();
    {
        float acc = 0.f;
        for (int e = g * 16; e < g * 16 + 16; ++e)
            acc += zp[0][e] * W0[(65 + e) * H + t];
        zq[g][t] = acc;
    }
    __syncthreads();
    if (g == 0) {
        brow[32] = f2bf(W0[t]);
        brow[33] = f2bf(b0[t] + zq[0][t] + zq[1][t] + zq[2][t] + zq[3][t]);
    } else if (g == 1) {
        for (int k = 34; k < 64; ++k) brow[k] = 0;
    }
}

// ---------------------------------------------------------------------------
// Main: 4 waves/block; wave = 16 points, one channel per c-iter.
// launch_bounds(256,2): VGPR cap 128 -> 4 waves/SIMD IF no spill.
// (Tier map measured R1/R4/R5/R6: (256,1)->256, (256,2)->128, (256,3)->84,
// (256,4)->64. R5/R6 spilled at 84/64; this body's live peak ~110 fits 128.)
// VALU cut: packed bf16 cvt and in-place MFMA accumulation (no acc-copy
// movs). Frag loads batched in K-halves of 4.
// ---------------------------------------------------------------------------
__global__ __launch_bounds__(256, 2)
void main_kernel(const float* __restrict__ p,      // (B,P,3)
                 const float* __restrict__ pos,    // (B,3)
                 const float* __restrict__ W_feat, // (3,F)
                 const short* __restrict__ Bxt,    // (B,C,64s,64k) bf16 (perm cols)
                 const short* __restrict__ Wat,    // (5,64s,64k)
                 const short* __restrict__ Wbt,    // (5,64s,64k)
                 const float* __restrict__ ba,     // (5,H)
                 const float* __restrict__ bb,     // (5,H)
                 const float* __restrict__ Wout,   // (H,1)
                 const float* __restrict__ bout,   // (1,)
                 float* __restrict__ out)          // (B,P)
{
    const int wave = threadIdx.x >> 6;
    const int lane = threadIdx.x & 63;
    const int quad = lane >> 4;
    const int l16  = lane & 15;
    const int b    = blockIdx.y;
    const int base = blockIdx.x * 64 + wave * 16;

    __shared__ short lds[4][16 * RS];             // 9.2 KB
    short* buf = &lds[wave][0];

    // ---- point features -> A-frags
    bf16x8 a0, a1;
    {
        const float* pp = p + ((size_t)b * P + base + l16) * 3;
        float px = pp[0] - pos[b * 3 + 0];
        float py = pp[1] - pos[b * 3 + 1];
        float pz = pp[2] - pos[b * 3 + 2];
        float nrm = sqrtf(px * px + py * py + pz * pz);
        if (nrm > 0.5f) { float s = 0.5f / nrm; px *= s; py *= s; pz *= s; }
        float s2 = 0.f;
#pragma unroll
        for (int j = 0; j < 8; ++j) {
            int k = quad * 8 + j;
            float a = px * W_feat[k] + py * W_feat[F + k] + pz * W_feat[2 * F + k];
            a0[j] = f2bf(a);
            s2 += a * a;
        }
        s2 += __shfl_xor(s2, 16);
        s2 += __shfl_xor(s2, 32);
#pragma unroll
        for (int j = 0; j < 8; ++j) a1[j] = 0;
        if (quad == 0) { a1[0] = f2bf(s2); a1[1] = f2bf(1.0f); }
    }

    f32x4 pooled[4];
#pragma unroll
    for (int nt = 0; nt < 4; ++nt)
        pooled[nt] = (f32x4){-1e30f, -1e30f, -1e30f, -1e30f};

    const float4 ba0v = *(const float4*)(ba + 4 * l16);
    const float4 bb0v = *(const float4*)(bb + 4 * l16);

    const int fragOff = l16 * 64 + quad * 8;

    // =============== c-loop: one channel per iter ===========================
#pragma unroll 1
    for (int c = 0; c < C; ++c) {
        const short* bx = Bxt + ((size_t)(b * C + c)) * 4096;

        // ---- stage 1: x = A' @ Bx  (K-halves of 4 frags each)
        f32x4 x[4];
        {
            bf16x8 bw[4];
#pragma unroll
            for (int nt = 0; nt < 4; ++nt)
                bw[nt] = *(const bf16x8*)(bx + nt * 1024 + fragOff);
#pragma unroll
            for (int nt = 0; nt < 4; ++nt) {
                f32x4 acc = (f32x4){0.f, 0.f, 0.f, 0.f};
                x[nt] = __builtin_amdgcn_mfma_f32_16x16x32_bf16(a0, bw[nt], acc, 0, 0, 0);
            }
#pragma unroll
            for (int nt = 0; nt < 4; ++nt)
                bw[nt] = *(const bf16x8*)(bx + nt * 1024 + fragOff + 32);
#pragma unroll
            for (int nt = 0; nt < 4; ++nt)
                x[nt] = __builtin_amdgcn_mfma_f32_16x16x32_bf16(a1, bw[nt], x[nt], 0, 0, 0);
        }

        // ---- relu(x) -> LDS -> A-frags
#pragma unroll
        for (int r = 0; r < 4; ++r) {
            uint2 w;
            w.x = cvtpk(fmaxf(x[0][r], 0.f), fmaxf(x[1][r], 0.f));
            w.y = cvtpk(fmaxf(x[2][r], 0.f), fmaxf(x[3][r], 0.f));
            *(uint2*)(buf + (quad * 4 + r) * RS + 4 * l16) = w;
        }
        bf16x8 xa0 = *(const bf16x8*)(buf + l16 * RS + quad * 8);
        bf16x8 xa1 = *(const bf16x8*)(buf + l16 * RS + 32 + quad * 8);

        // ---- stage 2: h = relu(x) @ Wa0 + ba0
        f32x4 h[4];
        {
            bf16x8 wf[4];
#pragma unroll
            for (int nt = 0; nt < 4; ++nt)
                wf[nt] = *(const bf16x8*)(Wat + nt * 1024 + fragOff);
#pragma unroll
            for (int nt = 0; nt < 4; ++nt) {
                float bv = nt == 0 ? ba0v.x : nt == 1 ? ba0v.y : nt == 2 ? ba0v.z : ba0v.w;
                f32x4 acc = (f32x4){bv, bv, bv, bv};
                h[nt] = __builtin_amdgcn_mfma_f32_16x16x32_bf16(xa0, wf[nt], acc, 0, 0, 0);
            }
#pragma unroll
            for (int nt = 0; nt < 4; ++nt)
                wf[nt] = *(const bf16x8*)(Wat + nt * 1024 + fragOff + 32);
#pragma unroll
            for (int nt = 0; nt < 4; ++nt)
                h[nt] = __builtin_amdgcn_mfma_f32_16x16x32_bf16(xa1, wf[nt], h[nt], 0, 0, 0);
        }

        // ---- relu(h) -> LDS -> A-frags
#pragma unroll
        for (int r = 0; r < 4; ++r) {
            uint2 w;
            w.x = cvtpk(fmaxf(h[0][r], 0.f), fmaxf(h[1][r], 0.f));
            w.y = cvtpk(fmaxf(h[2][r], 0.f), fmaxf(h[3][r], 0.f));
            *(uint2*)(buf + (quad * 4 + r) * RS + 4 * l16) = w;
        }
        bf16x8 ha0 = *(const bf16x8*)(buf + l16 * RS + quad * 8);
        bf16x8 ha1 = *(const bf16x8*)(buf + l16 * RS + 32 + quad * 8);

        // ---- stage 3: pool( x + relu(h) @ Wb0 )   [bb0 deferred]
        {
            bf16x8 wf[4];
#pragma unroll
            for (int nt = 0; nt < 4; ++nt)
                wf[nt] = *(const bf16x8*)(Wbt + nt * 1024 + fragOff);
#pragma unroll
            for (int nt = 0; nt < 4; ++nt)
                x[nt] = __builtin_amdgcn_mfma_f32_16x16x32_bf16(ha0, wf[nt], x[nt], 0, 0, 0);
#pragma unroll
            for (int nt = 0; nt < 4; ++nt)
                wf[nt] = *(const bf16x8*)(Wbt + nt * 1024 + fragOff + 32);
#pragma unroll
            for (int nt = 0; nt < 4; ++nt) {
                x[nt] = __builtin_amdgcn_mfma_f32_16x16x32_bf16(ha1, wf[nt], x[nt], 0, 0, 0);
#pragma unroll
                for (int r = 0; r < 4; ++r)
                    pooled[nt][r] = fmaxf(pooled[nt][r], x[nt][r]);
            }
        }
    }

    // deferred bb0
#pragma unroll
    for (int nt = 0; nt < 4; ++nt) {
        float bv = nt == 0 ? bb0v.x : nt == 1 ? bb0v.y : nt == 2 ? bb0v.z : bb0v.w;
#pragma unroll
        for (int r = 0; r < 4; ++r) pooled[nt][r] += bv;
    }

    // =============== residual blocks 1..4 (rolled) ==========================
#pragma unroll 1
    for (int i = 1; i < 5; ++i) {
        const short* wa = Wat + i * 4096;
        const short* wb = Wbt + i * 4096;
        const float4 bai = *(const float4*)(ba + i * H + 4 * l16);
        const float4 bbi = *(const float4*)(bb + i * H + 4 * l16);

#pragma unroll
        for (int r = 0; r < 4; ++r) {
            uint2 w;
            w.x = cvtpk(fmaxf(pooled[0][r], 0.f), fmaxf(pooled[1][r], 0.f));
            w.y = cvtpk(fmaxf(pooled[2][r], 0.f), fmaxf(pooled[3][r], 0.f));
            *(uint2*)(buf + (quad * 4 + r) * RS + 4 * l16) = w;
        }
        bf16x8 xa0 = *(const bf16x8*)(buf + l16 * RS + quad * 8);
        bf16x8 xa1 = *(const bf16x8*)(buf + l16 * RS + 32 + quad * 8);

        f32x4 h[4];
        {
            bf16x8 wf[4];
#pragma unroll
            for (int nt = 0; nt < 4; ++nt)
                wf[nt] = *(const bf16x8*)(wa + nt * 1024 + fragOff);
#pragma unroll
            for (int nt = 0; nt < 4; ++nt) {
                float bv = nt == 0 ? bai.x : nt == 1 ? bai.y : nt == 2 ? bai.z : bai.w;
                f32x4 acc = (f32x4){bv, bv, bv, bv};
                h[nt] = __builtin_amdgcn_mfma_f32_16x16x32_bf16(xa0, wf[nt], acc, 0, 0, 0);
            }
#pragma unroll
            for (int nt = 0; nt < 4; ++nt)
                wf[nt] = *(const bf16x8*)(wa + nt * 1024 + fragOff + 32);
#pragma unroll
            for (int nt = 0; nt < 4; ++nt)
                h[nt] = __builtin_amdgcn_mfma_f32_16x16x32_bf16(xa1, wf[nt], h[nt], 0, 0, 0);
        }

#pragma unroll
        for (int r = 0; r < 4; ++r) {
            uint2 w;
            w.x = cvtpk(fmaxf(h[0][r], 0.f), fmaxf(h[1][r], 0.f));
            w.y = cvtpk(fmaxf(h[2][r], 0.f), fmaxf(h[3][r], 0.f));
            *(uint2*)(buf + (quad * 4 + r) * RS + 4 * l16) = w;
        }
        bf16x8 ha0 = *(const bf16x8*)(buf + l16 * RS + quad * 8);
        bf16x8 ha1 = *(const bf16x8*)(buf + l16 * RS + 32 + quad * 8);

        // pooled += bbi + relu(h) @ Wbi   (bias first, then in-place MFMA)
#pragma unroll
        for (int nt = 0; nt < 4; ++nt) {
            float bv = nt == 0 ? bbi.x : nt == 1 ? bbi.y : nt == 2 ? bbi.z : bbi.w;
#pragma unroll
            for (int r = 0; r < 4; ++r) pooled[nt][r] += bv;
        }
        {
            bf16x8 wf[4];
#pragma unroll
            for (int nt = 0; nt < 4; ++nt)
                wf[nt] = *(const bf16x8*)(wb + nt * 1024 + fragOff);
#pragma unroll
            for (int nt = 0; nt < 4; ++nt)
                pooled[nt] = __builtin_amdgcn_mfma_f32_16x16x32_bf16(ha0, wf[nt], pooled[nt], 0, 0, 0);
#pragma unroll
            for (int nt = 0; nt < 4; ++nt)
                wf[nt] = *(const bf16x8*)(wb + nt * 1024 + fragOff + 32);
#pragma unroll
            for (int nt = 0; nt < 4; ++nt)
                pooled[nt] = __builtin_amdgcn_mfma_f32_16x16x32_bf16(ha1, wf[nt], pooled[nt], 0, 0, 0);
        }
    }

    // =============== head ===================================================
    const float4 wo4 = *(const float4*)(Wout + 4 * l16);
    const float bo = bout[0];
    float o[4];
#pragma unroll
    for (int r = 0; r < 4; ++r) {
        float v = fmaxf(pooled[0][r], 0.f) * wo4.x
                + fmaxf(pooled[1][r], 0.f) * wo4.y
                + fmaxf(pooled[2][r], 0.f) * wo4.z
                + fmaxf(pooled[3][r], 0.f) * wo4.w;
        v += __shfl_xor(v, 1);
        v += __shfl_xor(v, 2);
        v += __shfl_xor(v, 4);
        v += __shfl_xor(v, 8);
        o[r] = v + bo;
    }
    if (l16 == 0) {
        *(float4*)(out + (size_t)b * P + base + quad * 4) =
            make_float4(o[0], o[1], o[2], o[3]);
    }
}

extern "C" void kernel_launch(void* const* d_in, const int* in_sizes, int n_in,
                              void* d_out, int out_size, void* d_ws, size_t ws_size,
                              hipStream_t stream) {
    const float* z      = (const float*)d_in[0];
    const float* pos    = (const float*)d_in[1];
    const float* p      = (const float*)d_in[2];
    const float* W_feat = (const float*)d_in[3];
    const float* W_dir  = (const float*)d_in[4];
    const float* W0     = (const float*)d_in[5];
    const float* b0     = (const float*)d_in[6];
    const float* Wa     = (const float*)d_in[7];
    const float* ba     = (const float*)d_in[8];
    const float* Wb     = (const float*)d_in[9];
    const float* bb     = (const float*)d_in[10];
    const float* Wout   = (const float*)d_in[11];
    const float* bout   = (const float*)d_in[12];
    float* out = (float*)d_out;

    short* wsS = (short*)d_ws;
    short* Bxt = wsS;                    // B*C*64*64 shorts
    short* Wat = wsS + 32 * 4096;        // 5*4096
    short* Wbt = Wat + 5 * 4096;         // 5*4096

    setup_kernel<<<112, 256, 0, stream>>>(z, W_dir, W0, b0, Wa, Wb, Bxt, Wat, Wbt);

    dim3 grid(P / 64, B);
    main_kernel<<<grid, 256, 0, stream>>>(p, pos, W_feat, Bxt, Wat, Wbt,
                                          ba, bb, Wout, bout, out);
}